// Round 1
// baseline (12456.880 us; speedup 1.0000x reference)
//
#include <hip/hip_runtime.h>
#include <stdint.h>

typedef _Float16 f16;
typedef _Float16 f16x8 __attribute__((ext_vector_type(8)));
typedef float f32x4 __attribute__((ext_vector_type(4)));

#define LN_EPS 1e-5f

// ---------------- chunked-barrier scan kernel ----------------
// 48 WGs = 4 chunks (16 batch rows each) x 12 WGs. Each WG owns 128 of the
// 1536 output cols; per wave: 32 cols, U-tile resident in 128 VGPRs.
// Per step: phase A (MFMA pre-act) -> chunk barrier -> phase B (LN/gates,
// one wave per row) -> chunk barrier.

__device__ __forceinline__ void bar_sync(uint32_t* cnt, uint32_t* gen,
                                         uint32_t n, uint32_t* mygen) {
  __syncthreads();
  if (threadIdx.x == 0) {
    uint32_t g = *mygen;
    uint32_t t = __hip_atomic_fetch_add(cnt, 1u, __ATOMIC_ACQ_REL,
                                        __HIP_MEMORY_SCOPE_AGENT);
    if (t == n - 1u) {
      __hip_atomic_store(cnt, 0u, __ATOMIC_RELAXED, __HIP_MEMORY_SCOPE_AGENT);
      __hip_atomic_store(gen, g + 1u, __ATOMIC_RELEASE, __HIP_MEMORY_SCOPE_AGENT);
    } else {
      while (__hip_atomic_load(gen, __ATOMIC_ACQUIRE,
                               __HIP_MEMORY_SCOPE_AGENT) < g + 1u) { }
    }
    *mygen = g + 1u;
  }
  __syncthreads();
}

__global__ __launch_bounds__(256, 1) void scan_kernel(
    const f16* __restrict__ X,   // [512][64][1536] input part (bias folded)
    const f16* __restrict__ U,   // [1536][512] = [u_rz; u_h] fp16
    const float* __restrict__ lng_rz, const float* __restrict__ lnb_rz,
    const float* __restrict__ lng_h,  const float* __restrict__ lnb_h,
    f16* __restrict__ h16,       // [64][512] current h (fp16, MFMA operand)
    float* __restrict__ h32,     // [64][512] current h (fp32 master)
    f16* __restrict__ h_all,     // [512][64][512] all h outputs (fp16)
    float* __restrict__ pre,     // [64][1536] pre-activation scratch
    uint32_t* __restrict__ bars) // 4 chunk barriers, stride 128 u32
{
  const int chunk = blockIdx.x / 12;
  const int g     = blockIdx.x % 12;
  const int rows0 = chunk * 16;
  const int tid   = threadIdx.x;
  const int wid   = tid >> 6;
  const int lane  = tid & 63;
  const int quad  = lane >> 4;
  const int l16   = lane & 15;
  const int n_wg   = g * 128;
  const int n_wave = n_wg + wid * 32;
  const bool has_x = (n_wg < 1024);   // cols >=1024 are pure h@u_h (no X add)

  __shared__ f16 Ash[16][520];  // h rows, padded (2-way banks only)

  // Preload U fragments for this wave's 32 cols, whole K=512 -> 128 VGPRs.
  f16x8 uf[2][16];
#pragma unroll
  for (int c = 0; c < 2; ++c) {
#pragma unroll
    for (int kk = 0; kk < 16; ++kk) {
      const f16* p = U + (size_t)(n_wave + c * 16 + l16) * 512 + kk * 32 + quad * 8;
      uf[c][kk] = *(const f16x8*)p;
    }
  }

  uint32_t* cnt = bars + (size_t)chunk * 128;
  uint32_t* gen = cnt + 64;
  uint32_t mygen = 0;

  const int arow = tid >> 4;          // staging: 16 rows
  const int akb  = (tid & 15) * 32;   // 32 halves per thread

  for (int t = 0; t < 512; ++t) {
    // ---- phase A: pre = X[t] + h @ U^T (for this WG's cols) ----
    f32x4 acc[2];
    if (has_x) {
      const size_t xbase = ((size_t)t * 64 + rows0 + quad * 4) * 1536 + n_wave + l16;
#pragma unroll
      for (int c = 0; c < 2; ++c)
#pragma unroll
        for (int rr = 0; rr < 4; ++rr)
          acc[c][rr] = (float)X[xbase + (size_t)rr * 1536 + c * 16];
    } else {
#pragma unroll
      for (int c = 0; c < 2; ++c) acc[c] = (f32x4){0.f, 0.f, 0.f, 0.f};
    }
    {
      const f16* src = h16 + (size_t)(rows0 + arow) * 512 + akb;
#pragma unroll
      for (int j = 0; j < 4; ++j)
        *(f16x8*)&Ash[arow][akb + j * 8] = *(const f16x8*)(src + j * 8);
    }
    __syncthreads();
#pragma unroll
    for (int kk = 0; kk < 16; ++kk) {
      f16x8 af = *(const f16x8*)&Ash[l16][kk * 32 + quad * 8];
      acc[0] = __builtin_amdgcn_mfma_f32_16x16x32_f16(af, uf[0][kk], acc[0], 0, 0, 0);
      acc[1] = __builtin_amdgcn_mfma_f32_16x16x32_f16(af, uf[1][kk], acc[1], 0, 0, 0);
    }
#pragma unroll
    for (int c = 0; c < 2; ++c)
#pragma unroll
      for (int rr = 0; rr < 4; ++rr)
        pre[(size_t)(rows0 + quad * 4 + rr) * 1536 + n_wave + c * 16 + l16] = acc[c][rr];

    bar_sync(cnt, gen, 12, &mygen);

    // ---- phase B: LN + gates, one wave per batch row (WGs g<4) ----
    if (g < 4) {
      const int r = rows0 + g * 4 + wid;
      const float* prow = pre + (size_t)r * 1536;
      float v[16];
      float s1 = 0.f, s2 = 0.f;
#pragma unroll
      for (int i = 0; i < 16; ++i) v[i] = prow[i * 64 + lane];
#pragma unroll
      for (int i = 0; i < 16; ++i) { s1 += v[i]; s2 += v[i] * v[i]; }
#pragma unroll
      for (int off = 1; off < 64; off <<= 1) {
        s1 += __shfl_xor(s1, off); s2 += __shfl_xor(s2, off);
      }
      float m    = s1 * (1.f / 1024.f);
      float var  = s2 * (1.f / 1024.f) - m * m;
      float rstd = rsqrtf(var + LN_EPS);
      float rg[8], zg[8];
#pragma unroll
      for (int i = 0; i < 16; ++i) {
        int n = i * 64 + lane;
        float a = (v[i] - m) * rstd * lng_rz[n] + lnb_rz[n];
        float s = 1.f / (1.f + __expf(-a));
        if (i < 8) rg[i] = s; else zg[i - 8] = s;
      }
      const f16* xh = X + ((size_t)t * 64 + r) * 1536 + 1024;
      float ht[8];
      float u1 = 0.f, u2 = 0.f;
#pragma unroll
      for (int i = 0; i < 8; ++i) {
        int n = i * 64 + lane;
        float hu = prow[1024 + n];
        float hv = (float)xh[n] + rg[i] * hu;
        ht[i] = hv; u1 += hv; u2 += hv * hv;
      }
#pragma unroll
      for (int off = 1; off < 64; off <<= 1) {
        u1 += __shfl_xor(u1, off); u2 += __shfl_xor(u2, off);
      }
      float m2    = u1 * (1.f / 512.f);
      float var2  = u2 * (1.f / 512.f) - m2 * m2;
      float rstd2 = rsqrtf(var2 + LN_EPS);
#pragma unroll
      for (int i = 0; i < 8; ++i) {
        int n = i * 64 + lane;
        float a  = (ht[i] - m2) * rstd2 * lng_h[n] + lnb_h[n];
        float th = tanhf(a);
        float hp = h32[(size_t)r * 512 + n];
        float hn = (1.f - zg[i]) * hp + zg[i] * th;
        h32[(size_t)r * 512 + n] = hn;
        h16[(size_t)r * 512 + n] = (f16)hn;
        h_all[((size_t)t * 64 + r) * 512 + n] = (f16)hn;
      }
    }
    bar_sync(cnt, gen, 12, &mygen);
  }
}

// ---------------- generic K=512 fp16 GEMM: C = A @ W^T + bias ----------------
// A: [R][512] f16 row-major, W: [N][512] f16 row-major.
// mode 0: store f16 to out[r*N + n]  (X buffers)
// mode 1: store f32 logits: r=(t*64+b) -> out[((b*512)+t)*512 + n]
__global__ void gemm_k512(const f16* __restrict__ A, const f16* __restrict__ W,
                          const float* __restrict__ bias, void* __restrict__ out,
                          int N, int mode)
{
  __shared__ f16 As[128][56];
  __shared__ f16 Bs[128][56];
  const int tid = threadIdx.x;
  const int wid = tid >> 6, lane = tid & 63, quad = lane >> 4, l16 = lane & 15;
  const int wm = wid & 1, wn = wid >> 1;
  const int rb = blockIdx.y * 128, cb = blockIdx.x * 128;
  f32x4 acc[4][4];
#pragma unroll
  for (int i = 0; i < 4; ++i)
#pragma unroll
    for (int j = 0; j < 4; ++j) acc[i][j] = (f32x4){0.f, 0.f, 0.f, 0.f};
  const int srow = tid >> 1;
  const int skh  = (tid & 1) * 16;
  for (int kk = 0; kk < 16; ++kk) {
    __syncthreads();
    {
      const f16* a = A + (size_t)(rb + srow) * 512 + kk * 32 + skh;
      *(f16x8*)&As[srow][skh]     = *(const f16x8*)(a);
      *(f16x8*)&As[srow][skh + 8] = *(const f16x8*)(a + 8);
      const f16* b = W + (size_t)(cb + srow) * 512 + kk * 32 + skh;
      *(f16x8*)&Bs[srow][skh]     = *(const f16x8*)(b);
      *(f16x8*)&Bs[srow][skh + 8] = *(const f16x8*)(b + 8);
    }
    __syncthreads();
    f16x8 af[4], bf[4];
#pragma unroll
    for (int mt = 0; mt < 4; ++mt) af[mt] = *(const f16x8*)&As[wm * 64 + mt * 16 + l16][quad * 8];
#pragma unroll
    for (int nt = 0; nt < 4; ++nt) bf[nt] = *(const f16x8*)&Bs[wn * 64 + nt * 16 + l16][quad * 8];
#pragma unroll
    for (int mt = 0; mt < 4; ++mt)
#pragma unroll
      for (int nt = 0; nt < 4; ++nt)
        acc[mt][nt] = __builtin_amdgcn_mfma_f32_16x16x32_f16(af[mt], bf[nt], acc[mt][nt], 0, 0, 0);
  }
#pragma unroll
  for (int mt = 0; mt < 4; ++mt) {
#pragma unroll
    for (int nt = 0; nt < 4; ++nt) {
#pragma unroll
      for (int rr = 0; rr < 4; ++rr) {
        int grow = rb + wm * 64 + mt * 16 + quad * 4 + rr;
        int gcol = cb + wn * 64 + nt * 16 + l16;
        float vv = acc[mt][nt][rr] + bias[gcol];
        if (mode == 0) {
          ((f16*)out)[(size_t)grow * N + gcol] = (f16)vv;
        } else {
          int b = grow & 63, tt = grow >> 6;
          ((float*)out)[((size_t)b * 512 + tt) * 512 + gcol] = vv;
        }
      }
    }
  }
}

// ---------------- prep: fp16 conversion, transposes, zero-init ----------------
__global__ void prep_kernel(
    const float* __restrict__ x, const float* __restrict__ fc_w,
    const float* __restrict__ w_rz0, const float* __restrict__ b_rz0,
    const float* __restrict__ u_rz0, const float* __restrict__ w_h0,
    const float* __restrict__ b_h0,  const float* __restrict__ u_h0,
    const float* __restrict__ w_rz1, const float* __restrict__ b_rz1,
    const float* __restrict__ u_rz1, const float* __restrict__ w_h1,
    const float* __restrict__ b_h1,  const float* __restrict__ u_h1,
    f16* x16, f16* wcat0, f16* ucat0, f16* wcat1, f16* ucat1, f16* fcw16,
    float* bias0, float* bias1,
    f16* h16_0, f16* h16_1, float* h32_0, float* h32_1, uint32_t* bars)
{
  const int stride = gridDim.x * blockDim.x;
  const int gid = blockIdx.x * blockDim.x + threadIdx.x;
  // x (B,S,D) -> x16 [t][b][k]
  for (int i = gid; i < 16777216; i += stride) {
    int k = i & 511, b = (i >> 9) & 63, t = i >> 15;
    x16[i] = (f16)x[(((size_t)b << 9) + t) * 512 + k];
  }
  // concatenated weights [w_rz; w_h], [u_rz; u_h] per layer
  for (int i = gid; i < 786432; i += stride) {
    int n = i >> 9, k = i & 511;
    float a0 = (n < 1024) ? w_rz0[(size_t)n * 512 + k] : w_h0[(size_t)(n - 1024) * 512 + k];
    float c0 = (n < 1024) ? u_rz0[(size_t)n * 512 + k] : u_h0[(size_t)(n - 1024) * 512 + k];
    float a1 = (n < 1024) ? w_rz1[(size_t)n * 512 + k] : w_h1[(size_t)(n - 1024) * 512 + k];
    float c1 = (n < 1024) ? u_rz1[(size_t)n * 512 + k] : u_h1[(size_t)(n - 1024) * 512 + k];
    wcat0[i] = (f16)a0; ucat0[i] = (f16)c0; wcat1[i] = (f16)a1; ucat1[i] = (f16)c1;
  }
  for (int i = gid; i < 262144; i += stride) fcw16[i] = (f16)fc_w[i];
  for (int i = gid; i < 1536; i += stride) {
    bias0[i] = (i < 1024) ? b_rz0[i] : b_h0[i - 1024];
    bias1[i] = (i < 1024) ? b_rz1[i] : b_h1[i - 1024];
  }
  for (int i = gid; i < 32768; i += stride) {
    h16_0[i] = (f16)0.f; h16_1[i] = (f16)0.f; h32_0[i] = 0.f; h32_1[i] = 0.f;
  }
  for (int i = gid; i < 1024; i += stride) bars[i] = 0u;
}

// ---------------- tail: hidden = stack([h0, h1]) -> d_out[16777216..] -------
__global__ void tail_kernel(const float* __restrict__ h32_0,
                            const float* __restrict__ h32_1,
                            float* __restrict__ out)
{
  int i = blockIdx.x * blockDim.x + threadIdx.x;
  if (i < 32768)      out[16777216 + i] = h32_0[i];
  else if (i < 65536) out[16777216 + i] = h32_1[i - 32768];
}

extern "C" void kernel_launch(void* const* d_in, const int* in_sizes, int n_in,
                              void* d_out, int out_size, void* d_ws, size_t ws_size,
                              hipStream_t stream)
{
  const float* x      = (const float*)d_in[0];
  const float* fc_w   = (const float*)d_in[1];
  const float* fc_b   = (const float*)d_in[2];
  const float* l0_w_rz = (const float*)d_in[3];
  const float* l0_b_rz = (const float*)d_in[4];
  const float* l0_u_rz = (const float*)d_in[5];
  const float* l0_w_h  = (const float*)d_in[6];
  const float* l0_b_h  = (const float*)d_in[7];
  const float* l0_u_h  = (const float*)d_in[8];
  const float* l0_g_rz = (const float*)d_in[9];
  const float* l0_be_rz= (const float*)d_in[10];
  const float* l0_g_h  = (const float*)d_in[11];
  const float* l0_be_h = (const float*)d_in[12];
  const float* l1_w_rz = (const float*)d_in[13];
  const float* l1_b_rz = (const float*)d_in[14];
  const float* l1_u_rz = (const float*)d_in[15];
  const float* l1_w_h  = (const float*)d_in[16];
  const float* l1_b_h  = (const float*)d_in[17];
  const float* l1_u_h  = (const float*)d_in[18];
  const float* l1_g_rz = (const float*)d_in[19];
  const float* l1_be_rz= (const float*)d_in[20];
  const float* l1_g_h  = (const float*)d_in[21];
  const float* l1_be_h = (const float*)d_in[22];

  char* ws = (char*)d_ws;
  size_t off = 0;
  auto alloc = [&](size_t bytes) {
    size_t o = off; off += (bytes + 255) & ~(size_t)255; return o;
  };
  f16*   X      = (f16*)  (ws + alloc((size_t)512 * 64 * 1536 * 2)); // 100.7MB, reused X0/X1
  f16*   x16    = (f16*)  (ws + alloc((size_t)512 * 64 * 512 * 2));
  f16*   h_all0 = (f16*)  (ws + alloc((size_t)512 * 64 * 512 * 2));
  f16*   h_all1 = (f16*)  (ws + alloc((size_t)512 * 64 * 512 * 2));
  f16*   wcat0  = (f16*)  (ws + alloc((size_t)1536 * 512 * 2));
  f16*   ucat0  = (f16*)  (ws + alloc((size_t)1536 * 512 * 2));
  f16*   wcat1  = (f16*)  (ws + alloc((size_t)1536 * 512 * 2));
  f16*   ucat1  = (f16*)  (ws + alloc((size_t)1536 * 512 * 2));
  f16*   fcw16  = (f16*)  (ws + alloc((size_t)512 * 512 * 2));
  float* bias0  = (float*)(ws + alloc((size_t)1536 * 4));
  float* bias1  = (float*)(ws + alloc((size_t)1536 * 4));
  f16*   h16_0  = (f16*)  (ws + alloc((size_t)64 * 512 * 2));
  f16*   h16_1  = (f16*)  (ws + alloc((size_t)64 * 512 * 2));
  float* h32_0  = (float*)(ws + alloc((size_t)64 * 512 * 4));
  float* h32_1  = (float*)(ws + alloc((size_t)64 * 512 * 4));
  float* pre0   = (float*)(ws + alloc((size_t)64 * 1536 * 4));
  float* pre1   = (float*)(ws + alloc((size_t)64 * 1536 * 4));
  uint32_t* bars= (uint32_t*)(ws + alloc((size_t)1024 * 4));

  prep_kernel<<<dim3(2048), dim3(256), 0, stream>>>(
      x, fc_w, l0_w_rz, l0_b_rz, l0_u_rz, l0_w_h, l0_b_h, l0_u_h,
      l1_w_rz, l1_b_rz, l1_u_rz, l1_w_h, l1_b_h, l1_u_h,
      x16, wcat0, ucat0, wcat1, ucat1, fcw16, bias0, bias1,
      h16_0, h16_1, h32_0, h32_1, bars);

  // X0 = x @ [w_rz0; w_h0]^T + bias0
  gemm_k512<<<dim3(12, 256), dim3(256), 0, stream>>>(x16, wcat0, bias0, X, 1536, 0);
  // layer-0 scan
  scan_kernel<<<dim3(48), dim3(256), 0, stream>>>(
      X, ucat0, l0_g_rz, l0_be_rz, l0_g_h, l0_be_h,
      h16_0, h32_0, h_all0, pre0, bars);
  // X1 = h0_all @ [w_rz1; w_h1]^T + bias1
  gemm_k512<<<dim3(12, 256), dim3(256), 0, stream>>>(h_all0, wcat1, bias1, X, 1536, 0);
  // layer-1 scan
  scan_kernel<<<dim3(48), dim3(256), 0, stream>>>(
      X, ucat1, l1_g_rz, l1_be_rz, l1_g_h, l1_be_h,
      h16_1, h32_1, h_all1, pre1, bars + 512);
  // logits = h1_all @ fc_w^T + fc_b  (written B-major into d_out)
  gemm_k512<<<dim3(4, 256), dim3(256), 0, stream>>>(h_all1, fcw16, fc_b, d_out, 512, 1);
  // hidden states
  tail_kernel<<<dim3(256), dim3(256), 0, stream>>>(h32_0, h32_1, (float*)d_out);
}